// Round 2
// baseline (906.740 us; speedup 1.0000x reference)
//
#include <hip/hip_runtime.h>

// Committee vote histogram:
//   logits[m,b,c] = x[b,:] . W[m,:,c] + bias[m,c]
//   votes[m,b]    = argmax_c logits
//   out[b,c]      = #{ m : votes[m,b] == c }   (float32)
//
// B=65536, D=512, M=16, C=10.
// Block = 1024 threads (16 waves), one model per wave (W via wave-uniform
// scalar loads), 128 rows of x per block (2 row-groups per wave, doubling
// W reuse). x staged in LDS, double-buffered, loads issued one chunk ahead
// so HBM latency hides under the FMA stream (T14 async-stage split).

#define DDIM    512
#define NCLS    10
#define ROWS    128      // rows per block
#define ROWP    129      // float4 row stride (odd -> min bank aliasing)
#define KCHUNK  64
#define NCHUNK  (DDIM / KCHUNK)   // 8

__global__ __launch_bounds__(1024, 8)
void committee_kernel(const float* __restrict__ x,
                      const float* __restrict__ W,
                      const float* __restrict__ bias,
                      float* __restrict__ out)
{
    // xs[buf][kq][row]: x[row][k0 + 4*kq .. +3] for the current chunk
    __shared__ float4 xs[2][16][ROWP];
    __shared__ int ihist[ROWS * NCLS];

    const int tid  = threadIdx.x;
    const int row0 = blockIdx.x * ROWS;

    for (int i = tid; i < ROWS * NCLS; i += 1024) ihist[i] = 0;

    const int m    = __builtin_amdgcn_readfirstlane(tid >> 6);  // wave = model
    const int lane = tid & 63;

    const float* wp = W + (size_t)m * DDIM * NCLS;

    float acc[2][NCLS];
#pragma unroll
    for (int c = 0; c < NCLS; ++c) {
        const float bv = bias[m * NCLS + c];
        acc[0][c] = bv;
        acc[1][c] = bv;
    }

    // staging mapping: thread t stages rows (t>>4) and (t>>4)+64, kq = t&15
    const int srow = tid >> 4;   // 0..63
    const int skq  = tid & 15;   // 0..15
    const float* gsrc = x + (size_t)(row0 + srow) * DDIM + (skq << 2);

    // prologue: stage chunk 0, issue loads for chunk 1
    float4 pa = *reinterpret_cast<const float4*>(gsrc);
    float4 pb = *reinterpret_cast<const float4*>(gsrc + (size_t)64 * DDIM);
    xs[0][skq][srow]      = pa;
    xs[0][skq][64 + srow] = pb;
    pa = *reinterpret_cast<const float4*>(gsrc + KCHUNK);
    pb = *reinterpret_cast<const float4*>(gsrc + (size_t)64 * DDIM + KCHUNK);

    for (int ch = 0; ch < NCHUNK; ++ch) {
        __syncthreads();  // buf[ch&1] writes visible; buf[(ch+1)&1] readers done
        const int cur = ch & 1;

#pragma unroll
        for (int kq = 0; kq < 16; ++kq) {
            const float4 x0 = xs[cur][kq][lane];
            const float4 x1 = xs[cur][kq][64 + lane];
            const float xa[4] = {x0.x, x0.y, x0.z, x0.w};
            const float xb[4] = {x1.x, x1.y, x1.z, x1.w};
            const float* wk = wp + (size_t)(ch * KCHUNK + (kq << 2)) * NCLS;
#pragma unroll
            for (int j = 0; j < 4; ++j) {
                const float a0 = xa[j];
                const float a1 = xb[j];
#pragma unroll
                for (int c = 0; c < NCLS; ++c) {
                    const float w = wk[j * NCLS + c];
                    acc[0][c] = fmaf(a0, w, acc[0][c]);
                    acc[1][c] = fmaf(a1, w, acc[1][c]);
                }
            }
        }

        if (ch + 1 < NCHUNK) {
            // write the prefetched chunk (vmcnt wait lands here, after compute)
            xs[cur ^ 1][skq][srow]      = pa;
            xs[cur ^ 1][skq][64 + srow] = pb;
            if (ch + 2 < NCHUNK) {
                pa = *reinterpret_cast<const float4*>(gsrc + (size_t)(ch + 2) * KCHUNK);
                pb = *reinterpret_cast<const float4*>(gsrc + (size_t)64 * DDIM
                                                      + (size_t)(ch + 2) * KCHUNK);
            }
        }
    }

    // argmax with first-occurrence-of-max semantics (strict >)
#pragma unroll
    for (int g = 0; g < 2; ++g) {
        int best = 0;
        float bv = acc[g][0];
#pragma unroll
        for (int c = 1; c < NCLS; ++c) {
            if (acc[g][c] > bv) { bv = acc[g][c]; best = c; }
        }
        atomicAdd(&ihist[(g * 64 + lane) * NCLS + best], 1);
    }
    __syncthreads();

    for (int i = tid; i < ROWS * NCLS; i += 1024) {
        out[(size_t)row0 * NCLS + i] = (float)ihist[i];
    }
}

extern "C" void kernel_launch(void* const* d_in, const int* in_sizes, int n_in,
                              void* d_out, int out_size, void* d_ws, size_t ws_size,
                              hipStream_t stream) {
    const float* x  = (const float*)d_in[0];   // [65536, 512]
    const float* W  = (const float*)d_in[1];   // [16, 512, 10]
    const float* b  = (const float*)d_in[2];   // [16, 10]
    float* out      = (float*)d_out;           // [65536, 10]

    const int nblocks = 65536 / ROWS;          // 512
    committee_kernel<<<nblocks, 1024, 0, stream>>>(x, W, b, out);
}

// Round 3
// 166.857 us; speedup vs baseline: 5.4342x; 5.4342x over previous
//
#include <hip/hip_runtime.h>

// Committee vote histogram:
//   logits[m,b,c] = x[b,:] . W[m,:,c] + bias[m,c]
//   votes[m,b]    = argmax_c logits
//   out[b,c]      = #{ m : votes[m,b] == c }   (float32)
//
// B=65536, D=512, M=16, C=10.
// Round-1 structure (proven no-scratch codegen: 64 rows/block, one model per
// wave, W via wave-uniform scalar loads, fully unrolled 640-FMA chunk body)
// + double-buffered LDS with register prefetch one chunk ahead so HBM latency
// hides under the FMA stream. One barrier per chunk.

#define NB_ROWS 64
#define DDIM    512
#define NCLS    10
#define KCHUNK  64
#define NCHUNK  (DDIM / KCHUNK)   // 8

__global__ __launch_bounds__(1024, 2)
void committee_kernel(const float* __restrict__ x,
                      const float* __restrict__ W,
                      const float* __restrict__ bias,
                      float* __restrict__ out)
{
    // xs[buf][kq][row]: x[row][ch*64 + 4*kq .. +3]
    __shared__ float4 xs[2][16][65];
    __shared__ int ihist[NB_ROWS * NCLS];

    const int tid  = threadIdx.x;
    const int row0 = blockIdx.x * NB_ROWS;

    if (tid < NB_ROWS * NCLS) ihist[tid] = 0;

    const int m    = __builtin_amdgcn_readfirstlane(tid >> 6);  // wave = model
    const int lane = tid & 63;                                  // row in tile

    const float* wp = W + (size_t)m * DDIM * NCLS;

    float acc[NCLS];
#pragma unroll
    for (int c = 0; c < NCLS; ++c) acc[c] = bias[m * NCLS + c];

    // staging: thread t loads x[row0 + t/16][4*(t%16) .. +3] of each chunk
    const int srow = tid >> 4;   // 0..63
    const int skq  = tid & 15;   // 0..15
    const float* gsrc = x + (size_t)(row0 + srow) * DDIM + (skq << 2);

    // prologue: stage chunk 0 directly, issue load for chunk 1
    float4 pa = *reinterpret_cast<const float4*>(gsrc);
    xs[0][skq][srow] = pa;
    pa = *reinterpret_cast<const float4*>(gsrc + KCHUNK);

    for (int ch = 0; ch < NCHUNK; ++ch) {
        __syncthreads();           // prev iter's readers of buf[cur^1] done;
        const int cur = ch & 1;    // buf[cur] writes visible

        if (ch + 1 < NCHUNK) {
            // write prefetched chunk ch+1 (its load has had a full compute
            // phase to land), then immediately issue the load for ch+2
            xs[cur ^ 1][skq][srow] = pa;
            if (ch + 2 < NCHUNK) {
                pa = *reinterpret_cast<const float4*>(
                    gsrc + (size_t)(ch + 2) * KCHUNK);
            }
        }

#pragma unroll
        for (int kq = 0; kq < 16; ++kq) {
            const float4 xv = xs[cur][kq][lane];
            const float xarr[4] = {xv.x, xv.y, xv.z, xv.w};
            // W chunk for this wave's model: wave-uniform -> s_load
            const float* wk = wp + (size_t)(ch * KCHUNK + (kq << 2)) * NCLS;
#pragma unroll
            for (int j = 0; j < 4; ++j) {
                const float xj = xarr[j];
#pragma unroll
                for (int c = 0; c < NCLS; ++c)
                    acc[c] = fmaf(xj, wk[j * NCLS + c], acc[c]);
            }
        }
    }

    // argmax with first-occurrence-of-max semantics (strict >)
    int best = 0;
    float bv = acc[0];
#pragma unroll
    for (int c = 1; c < NCLS; ++c) {
        if (acc[c] > bv) { bv = acc[c]; best = c; }
    }

    atomicAdd(&ihist[lane * NCLS + best], 1);
    __syncthreads();

    if (tid < NB_ROWS * NCLS) {
        out[(size_t)row0 * NCLS + tid] = (float)ihist[tid];
    }
}

extern "C" void kernel_launch(void* const* d_in, const int* in_sizes, int n_in,
                              void* d_out, int out_size, void* d_ws, size_t ws_size,
                              hipStream_t stream) {
    const float* x  = (const float*)d_in[0];   // [65536, 512]
    const float* W  = (const float*)d_in[1];   // [16, 512, 10]
    const float* b  = (const float*)d_in[2];   // [16, 10]
    float* out      = (float*)d_out;           // [65536, 10]

    const int nblocks = 65536 / NB_ROWS;       // 1024
    committee_kernel<<<nblocks, 1024, 0, stream>>>(x, W, b, out);
}